// Round 7
// baseline (155.615 us; speedup 1.0000x reference)
//
#include <hip/hip_runtime.h>

typedef __bf16 bf16x8 __attribute__((ext_vector_type(8)));
typedef float f32x4 __attribute__((ext_vector_type(4)));
typedef unsigned int u32x4 __attribute__((ext_vector_type(4)));

__device__ __forceinline__ unsigned short f2bf(float f) {
  unsigned int u = __float_as_uint(f);
  u += 0x7FFFu + ((u >> 16) & 1u);   // round-to-nearest-even
  return (unsigned short)(u >> 16);
}

__device__ __forceinline__ bf16x8 load_frag(const unsigned short* p) {
  u32x4 v = *(const u32x4*)p;
  return __builtin_bit_cast(bf16x8, v);
}

__device__ __forceinline__ bf16x8 load_frag_lds(const char* p) {
  u32x4 v = *(const u32x4*)p;
  return __builtin_bit_cast(bf16x8, v);
}

// ---------------------------------------------------------------------------
// fp32 -> bf16 conversion of all four tensors (object dim zero-padded to a
// multiple of 16 for MFMA M-tiling). Verified R0-R5; bf16 panels measured
// faster than in-register fp32 convert (R4 post-mortem).
// ---------------------------------------------------------------------------
__global__ __launch_bounds__(256) void convert_all(
    const float* __restrict__ im, const float* __restrict__ s,
    const float* __restrict__ pred, const float* __restrict__ crp,
    unsigned short* __restrict__ imb, unsigned short* __restrict__ sb,
    unsigned short* __restrict__ pb, unsigned short* __restrict__ cb)
{
  int b = blockIdx.x;
  const float* src; unsigned short* dst; int O, OP, base;
  if (b < 768)       { src = im;   dst = imb; O = 36; OP = 48; base = 0; }
  else if (b < 1568) { src = s;    dst = sb;  O = 50; OP = 50; base = 768; }
  else if (b < 2080) { src = pred; dst = pb;  O = 25; OP = 32; base = 1568; }
  else               { src = crp;  dst = cb;  O = 30; OP = 30; base = 2080; }
  int tid = (b - base) * 256 + (int)threadIdx.x;          // one thread = 4 floats
  int total = 128 * OP * 32;
  if (tid >= total) return;
  int d4 = tid & 31;
  int o  = (tid >> 5) % OP;
  int bb = tid / (OP * 32);
  unsigned short r0 = 0, r1 = 0, r2 = 0, r3 = 0;
  if (o < O) {
    const float4 v = *(const float4*)(src + ((bb * O + o) << 7) + (d4 << 2));
    r0 = f2bf(v.x); r1 = f2bf(v.y); r2 = f2bf(v.z); r3 = f2bf(v.w);
  }
  ushort4 outv; outv.x = r0; outv.y = r1; outv.z = r2; outv.w = r3;
  *(ushort4*)(dst + (size_t)tid * 4) = outv;
}

// ---------------------------------------------------------------------------
// t2i pooled score, TWO images per block vs one 16-caption group.
// R6 design: A panel staged ONCE into LDS in FRAGMENT-MAJOR layout
// ([frag][lane] x 16B), so
//   * per-iteration A access is conflict-free ds_read_b128 (no L2 traffic --
//     kills the measured ~1.3 GB / ~37 us A-remat reload cost of the R0/R2
//     structure),
//   * register pressure stays ~110 VGPR -> 4 waves/SIMD -> 4 blocks/CU ->
//     all 1024 blocks resident in ONE round (R5's pinned-A version fell to
//     2 blocks/CU / two rounds and lost the traffic win back).
// B tiles double-buffered in two NAMED buffers (static indexing) on a
// stride-8 loop. Verified D mapping: col=lane&15, row=(lane>>4)*4+reg.
// ---------------------------------------------------------------------------
template<int MT, int W>
__device__ __forceinline__ void t2i_lds(
    const unsigned short* __restrict__ A,    // [128, MT*16, 128] bf16 panel
    const unsigned short* __restrict__ Bw,   // [128, W, 128] bf16 (flat rows)
    const int* __restrict__ obj_l, const int* __restrict__ cap_l,
    float* __restrict__ pooled,              // [128,128] fp32
    int vb, char* lds)
{
  constexpr int AFRAGS = 2 * MT * 4;         // 1024-B fragments in LDS
  constexpr int ACHUNK = AFRAGS * 64;        // 16-B lane chunks
  float* wmax = (float*)(lds + AFRAGS * 1024);   // [2][16*W]

  const int i0  = (vb >> 3) * 2;             // images 2*ig, 2*ig+1
  const int cg0 = (vb & 7) * 16;             // caption group base
  const int tid = threadIdx.x;
  const int wv = tid >> 6, lane = tid & 63;
  const int quad = lane >> 4, n16 = lane & 15;
  const int ol0 = obj_l[i0], ol1 = obj_l[i0 + 1];

  // ---- stage A panel -> LDS, fragment-major (linear, conflict-free) ----
  // chunk c = ((im*MT+t)*4+sf)*64 + quad*16 + n16  ->  lds[c*16 .. +15]
  for (int c = tid; c < ACHUNK; c += 256) {
    const int cn = c & 15, cq = (c >> 4) & 3, cs = (c >> 6) & 3;
    const int rest = c >> 8;
    const int ct = rest % MT, ci = rest / MT;
    const unsigned short* g =
        A + (((size_t)(i0 + ci) * (MT * 16) + ct * 16 + cn) << 7)
          + cq * 8 + cs * 32;
    *(u32x4*)(lds + (size_t)c * 16) = *(const u32x4*)g;
  }
  __syncthreads();

  const unsigned short* Bbase = Bw + (((size_t)cg0 * W + n16) << 7) + quad * 8;
  const char* abase = lds + lane * 16;       // + frag*1024 (static) per read

  bf16x8 bA[4], bB[4];
  {
    const unsigned short* p = Bbase + ((size_t)(wv * 16) << 7);
#pragma unroll
    for (int sf = 0; sf < 4; ++sf) bA[sf] = load_frag(p + sf * 32);
  }

  for (int nt = wv; nt < W; nt += 8) {
    const int ntB = nt + 4, ntA2 = nt + 8;
    if (ntB < W) {
      const unsigned short* p = Bbase + ((size_t)(ntB * 16) << 7);
#pragma unroll
      for (int sf = 0; sf < 4; ++sf) bB[sf] = load_frag(p + sf * 32);
    }

    // ---- compute tile nt with bA ----
    {
      f32x4 acc[2][MT];
#pragma unroll
      for (int i2 = 0; i2 < 2; ++i2)
#pragma unroll
        for (int t = 0; t < MT; ++t) { f32x4 z = {0.f,0.f,0.f,0.f}; acc[i2][t] = z; }
#pragma unroll
      for (int sf = 0; sf < 4; ++sf) {
#pragma unroll
        for (int i2 = 0; i2 < 2; ++i2)
#pragma unroll
          for (int t = 0; t < MT; ++t) {
            const bf16x8 af =
                load_frag_lds(abase + ((i2 * MT + t) * 4 + sf) * 1024);
            acc[i2][t] = __builtin_amdgcn_mfma_f32_16x16x32_bf16(
                af, bA[sf], acc[i2][t], 0, 0, 0);
          }
      }
#pragma unroll
      for (int i2 = 0; i2 < 2; ++i2) {
        const int ol = i2 ? ol1 : ol0;
        float m = -3.0e38f;
#pragma unroll
        for (int t = 0; t < MT; ++t)
#pragma unroll
          for (int r = 0; r < 4; ++r) {
            int o = t * 16 + quad * 4 + r;
            if (o < ol) m = fmaxf(m, acc[i2][t][r]);
          }
        m = fmaxf(m, __shfl_xor(m, 16));
        m = fmaxf(m, __shfl_xor(m, 32));
        if (quad == 0) wmax[i2 * (16 * W) + nt * 16 + n16] = m;
      }
    }

    if (ntA2 < W) {
      const unsigned short* p = Bbase + ((size_t)(ntA2 * 16) << 7);
#pragma unroll
      for (int sf = 0; sf < 4; ++sf) bA[sf] = load_frag(p + sf * 32);
    }

    // ---- compute tile ntB with bB ----
    if (ntB < W) {
      f32x4 acc[2][MT];
#pragma unroll
      for (int i2 = 0; i2 < 2; ++i2)
#pragma unroll
        for (int t = 0; t < MT; ++t) { f32x4 z = {0.f,0.f,0.f,0.f}; acc[i2][t] = z; }
#pragma unroll
      for (int sf = 0; sf < 4; ++sf) {
#pragma unroll
        for (int i2 = 0; i2 < 2; ++i2)
#pragma unroll
          for (int t = 0; t < MT; ++t) {
            const bf16x8 af =
                load_frag_lds(abase + ((i2 * MT + t) * 4 + sf) * 1024);
            acc[i2][t] = __builtin_amdgcn_mfma_f32_16x16x32_bf16(
                af, bB[sf], acc[i2][t], 0, 0, 0);
          }
      }
#pragma unroll
      for (int i2 = 0; i2 < 2; ++i2) {
        const int ol = i2 ? ol1 : ol0;
        float m = -3.0e38f;
#pragma unroll
        for (int t = 0; t < MT; ++t)
#pragma unroll
          for (int r = 0; r < 4; ++r) {
            int o = t * 16 + quad * 4 + r;
            if (o < ol) m = fmaxf(m, acc[i2][t][r]);
          }
        m = fmaxf(m, __shfl_xor(m, 16));
        m = fmaxf(m, __shfl_xor(m, 32));
        if (quad == 0) wmax[i2 * (16 * W) + ntB * 16 + n16] = m;
      }
    }
  }
  __syncthreads();

  if (tid < 32) {
    const int i2 = tid >> 4, c = tid & 15;
    const float* wp = wmax + i2 * (16 * W) + c * W;
    float ssum = 0.f;
    for (int w = 0; w < W; ++w) ssum += wp[w];
    const int cc = cg0 + c;
    pooled[((i0 + i2) << 7) + cc] = ssum / (float)cap_l[cc];
  }
}

// 1024 blocks, one part-slice each (parallel layout; serializing measured
// ~2x slower in R3). LDS: part1 = 24576 + 6400 = 30976 B -> 4 blocks/CU.
__global__ __launch_bounds__(256, 4) void t2i_both(
    const unsigned short* __restrict__ imb, const unsigned short* __restrict__ sb,
    const unsigned short* __restrict__ pb,  const unsigned short* __restrict__ cb,
    const int* __restrict__ im_l, const int* __restrict__ s_l,
    const int* __restrict__ pred_l, const int* __restrict__ crl,
    float* __restrict__ p1, float* __restrict__ p2)
{
  __shared__ __align__(16) char lds[24 * 1024 + 2 * 16 * 50 * 4];
  if (blockIdx.x < 512)
    t2i_lds<3, 50>(imb, sb, im_l, s_l, p1, (int)blockIdx.x, lds);
  else
    t2i_lds<2, 30>(pb, cb, pred_l, crl, p2, (int)blockIdx.x - 512, lds);
}

// ---------------------------------------------------------------------------
// Hinge loss, simplified form validated in R1-R5:
//   max_j relu(M + S[i][j] - diag[i]) over the diag-zeroed matrix
//     == relu(M + offdiag_max_j(S[i][j]) - diag[i])
// One 256-thread block; kernel boundary provides p1/p2 coherence.
// ---------------------------------------------------------------------------
__global__ __launch_bounds__(256) void loss_kernel(
    const float* __restrict__ p1, const float* __restrict__ p2,
    float* __restrict__ out)
{
  __shared__ float cmax[2][128];
  __shared__ float rmax[2][128];
  __shared__ float wsum[2];
  const int tid = threadIdx.x;
  const int h = tid >> 7, j = tid & 127;

  {  // column off-diagonal max (coalesced: lanes sweep j for fixed row)
    float cm = -3.0e38f;
    for (int rr = 0; rr < 64; ++rr) {
      const int row = h * 64 + rr;
      const float v = p1[row * 128 + j] + p2[row * 128 + j];
      cm = (row == j) ? cm : fmaxf(cm, v);
    }
    cmax[h][j] = cm;
  }
  {  // row off-diagonal max (thread (h, i=j) scans its 64-col half of row i)
    float rm = -3.0e38f;
    for (int k = 0; k < 64; ++k) {
      const int c = h * 64 + k;
      const float v = p1[j * 128 + c] + p2[j * 128 + c];
      rm = (c == j) ? rm : fmaxf(rm, v);
    }
    rmax[h][j] = rm;
  }
  __syncthreads();

  float v = 0.f;
  if (tid < 128) {
    const float d  = p1[tid * 129] + p2[tid * 129];
    const float rm = fmaxf(rmax[0][tid], rmax[1][tid]);
    const float cm = fmaxf(cmax[0][tid], cmax[1][tid]);
    v = fmaxf(0.2f + rm - d, 0.f) + fmaxf(0.2f + cm - d, 0.f);
  }
#pragma unroll
  for (int o = 32; o; o >>= 1) v += __shfl_xor(v, o);
  if (tid == 0)  wsum[0] = v;
  if (tid == 64) wsum[1] = v;
  __syncthreads();
  if (tid == 0) out[0] = wsum[0] + wsum[1];
}

// ---------------------------------------------------------------------------
extern "C" void kernel_launch(void* const* d_in, const int* in_sizes, int n_in,
                              void* d_out, int out_size, void* d_ws, size_t ws_size,
                              hipStream_t stream)
{
  const float* im     = (const float*)d_in[0];
  const int*   im_l   = (const int*)  d_in[1];
  const float* s      = (const float*)d_in[2];
  const int*   s_l    = (const int*)  d_in[3];
  const float* pred   = (const float*)d_in[4];
  const int*   pred_l = (const int*)  d_in[5];
  // d_in[6], d_in[7] unused by the reference.
  const float* crp    = (const float*)d_in[8];
  const int*   crl    = (const int*)  d_in[9];

  char* ws = (char*)d_ws;
  const size_t off_imb = 0;
  const size_t off_sb  = off_imb + (size_t)128 * 48 * 128 * 2;
  const size_t off_pb  = off_sb  + (size_t)128 * 50 * 128 * 2;
  const size_t off_cb  = off_pb  + (size_t)128 * 32 * 128 * 2;
  const size_t off_p1  = off_cb  + (size_t)128 * 30 * 128 * 2;
  const size_t off_p2  = off_p1  + (size_t)128 * 128 * 4;

  unsigned short* imb = (unsigned short*)(ws + off_imb);
  unsigned short* sb  = (unsigned short*)(ws + off_sb);
  unsigned short* pb  = (unsigned short*)(ws + off_pb);
  unsigned short* cb  = (unsigned short*)(ws + off_cb);
  float* p1 = (float*)(ws + off_p1);
  float* p2 = (float*)(ws + off_p2);

  hipLaunchKernelGGL(convert_all, dim3(2560), dim3(256), 0, stream,
                     im, s, pred, crp, imb, sb, pb, cb);
  hipLaunchKernelGGL(t2i_both, dim3(1024), dim3(256), 0, stream,
                     imb, sb, pb, cb, im_l, s_l, pred_l, crl, p1, p2);
  hipLaunchKernelGGL(loss_kernel, dim3(1), dim3(256), 0, stream,
                     p1, p2, (float*)d_out);
}

// Round 8
// 146.280 us; speedup vs baseline: 1.0638x; 1.0638x over previous
//
#include <hip/hip_runtime.h>

typedef __bf16 bf16x8 __attribute__((ext_vector_type(8)));
typedef float f32x4 __attribute__((ext_vector_type(4)));
typedef unsigned int u32x4 __attribute__((ext_vector_type(4)));

__device__ __forceinline__ unsigned short f2bf(float f) {
  unsigned int u = __float_as_uint(f);
  u += 0x7FFFu + ((u >> 16) & 1u);   // round-to-nearest-even
  return (unsigned short)(u >> 16);
}

__device__ __forceinline__ bf16x8 load_frag(const unsigned short* p) {
  u32x4 v = *(const u32x4*)p;
  return __builtin_bit_cast(bf16x8, v);
}

// Pin a fragment into VGPRs at this program point (defeats load-sink/remat;
// R2 evidence: VGPR_Count=76 -> A reloaded from L2 every iteration, ~37us).
__device__ __forceinline__ void keep(bf16x8& x) {
  asm volatile("" : "+v"(x));
}

// ---------------------------------------------------------------------------
// fp32 -> bf16 conversion of all four tensors (object dim zero-padded to a
// multiple of 16 for MFMA M-tiling). Verified R0-R7; bf16 panels measured
// faster than in-register fp32 convert (R4 post-mortem).
// ---------------------------------------------------------------------------
__global__ __launch_bounds__(256) void convert_all(
    const float* __restrict__ im, const float* __restrict__ s,
    const float* __restrict__ pred, const float* __restrict__ crp,
    unsigned short* __restrict__ imb, unsigned short* __restrict__ sb,
    unsigned short* __restrict__ pb, unsigned short* __restrict__ cb)
{
  int b = blockIdx.x;
  const float* src; unsigned short* dst; int O, OP, base;
  if (b < 768)       { src = im;   dst = imb; O = 36; OP = 48; base = 0; }
  else if (b < 1568) { src = s;    dst = sb;  O = 50; OP = 50; base = 768; }
  else if (b < 2080) { src = pred; dst = pb;  O = 25; OP = 32; base = 1568; }
  else               { src = crp;  dst = cb;  O = 30; OP = 30; base = 2080; }
  int tid = (b - base) * 256 + (int)threadIdx.x;          // one thread = 4 floats
  int total = 128 * OP * 32;
  if (tid >= total) return;
  int d4 = tid & 31;
  int o  = (tid >> 5) % OP;
  int bb = tid / (OP * 32);
  unsigned short r0 = 0, r1 = 0, r2 = 0, r3 = 0;
  if (o < O) {
    const float4 v = *(const float4*)(src + ((bb * O + o) << 7) + (d4 << 2));
    r0 = f2bf(v.x); r1 = f2bf(v.y); r2 = f2bf(v.z); r3 = f2bf(v.w);
  }
  ushort4 outv; outv.x = r0; outv.y = r1; outv.z = r2; outv.w = r3;
  *(ushort4*)(dst + (size_t)tid * 4) = outv;
}

// ---------------------------------------------------------------------------
// t2i pooled score, TWO images per block vs one 16-caption group.
// R8 design -- register-resident A with all known failure modes closed:
//  * A fragments (96 VGPR for MT=3) loaded once + keep()-pinned: per-iter
//    operand traffic is B-only (~4 B/output from L2), vs ~19 B/out LDS
//    streaming (R7, 52us) or ~24 B/out L2 remat (R0/R2, ~37us).
//  * __launch_bounds__(256,2): VGPR cap 256. R7's (256,4) made the backend
//    target 64 VGPR and spill 58 MB of scratch (WRITE_SIZE smoking gun).
//  * DYNAMIC stride-8 loop, two NAMED B buffers, two compute sections:
//    static register indexing without full-unroll pressure (R5's suspected
//    spill source).
// Verified D mapping: col=lane&15 (B-row), row=(lane>>4)*4+reg (object).
// ---------------------------------------------------------------------------
template<int MT, int W>
__device__ __forceinline__ void t2i_reg(
    const unsigned short* __restrict__ A,    // [128, MT*16, 128] bf16 panel
    const unsigned short* __restrict__ Bw,   // [128, W, 128] bf16 (flat rows)
    const int* __restrict__ obj_l, const int* __restrict__ cap_l,
    float* __restrict__ pooled,              // [128,128] fp32
    int vb, float* wmax)                     // wmax LDS >= 2*16*W
{
  const int i0  = (vb >> 3) * 2;             // images 2*ig, 2*ig+1
  const int cg0 = (vb & 7) * 16;             // caption group base
  const int tid = threadIdx.x;
  const int wv = tid >> 6, lane = tid & 63;
  const int quad = lane >> 4, n16 = lane & 15;
  const int ol0 = obj_l[i0], ol1 = obj_l[i0 + 1];

  // ---- A fragments: load once from bf16 panel, pin resident ----
  bf16x8 af[2][MT][4];
#pragma unroll
  for (int i2 = 0; i2 < 2; ++i2) {
    const unsigned short* Ab =
        A + (((size_t)(i0 + i2) * (MT * 16) + n16) << 7) + quad * 8;
#pragma unroll
    for (int t = 0; t < MT; ++t)
#pragma unroll
      for (int sf = 0; sf < 4; ++sf)
        af[i2][t][sf] = load_frag(Ab + ((t * 16) << 7) + sf * 32);
  }
#pragma unroll
  for (int i2 = 0; i2 < 2; ++i2)
#pragma unroll
    for (int t = 0; t < MT; ++t)
#pragma unroll
      for (int sf = 0; sf < 4; ++sf)
        keep(af[i2][t][sf]);

  const unsigned short* Bbase = Bw + (((size_t)cg0 * W + n16) << 7) + quad * 8;

  // one 16x16 output tile: MFMA over K=128 with B frags bf, then masked
  // object-max -> wmax row nt
  auto compute_tile = [&](int nt, const bf16x8 (&bf)[4]) {
    f32x4 acc[2][MT];
#pragma unroll
    for (int i2 = 0; i2 < 2; ++i2)
#pragma unroll
      for (int t = 0; t < MT; ++t) { f32x4 z = {0.f,0.f,0.f,0.f}; acc[i2][t] = z; }
#pragma unroll
    for (int sf = 0; sf < 4; ++sf)
#pragma unroll
      for (int i2 = 0; i2 < 2; ++i2)
#pragma unroll
        for (int t = 0; t < MT; ++t)
          acc[i2][t] = __builtin_amdgcn_mfma_f32_16x16x32_bf16(
              af[i2][t][sf], bf[sf], acc[i2][t], 0, 0, 0);
#pragma unroll
    for (int i2 = 0; i2 < 2; ++i2) {
      const int ol = i2 ? ol1 : ol0;
      float m = -3.0e38f;
#pragma unroll
      for (int t = 0; t < MT; ++t)
#pragma unroll
        for (int r = 0; r < 4; ++r) {
          int o = t * 16 + quad * 4 + r;
          if (o < ol) m = fmaxf(m, acc[i2][t][r]);
        }
      m = fmaxf(m, __shfl_xor(m, 16));
      m = fmaxf(m, __shfl_xor(m, 32));
      if (quad == 0) wmax[i2 * (16 * W) + nt * 16 + n16] = m;
    }
  };

  // ---- stride-8 loop, two named B buffers (prefetch distance 1 tile) ----
  bf16x8 bA[4], bB[4];
  {
    const unsigned short* p = Bbase + ((size_t)(wv * 16) << 7);
#pragma unroll
    for (int sf = 0; sf < 4; ++sf) bA[sf] = load_frag(p + sf * 32);
  }
  for (int nt = wv; nt < W; nt += 8) {
    const int ntB = nt + 4;
    if (ntB < W) {
      const unsigned short* p = Bbase + ((size_t)(ntB * 16) << 7);
#pragma unroll
      for (int sf = 0; sf < 4; ++sf) bB[sf] = load_frag(p + sf * 32);
    }
    compute_tile(nt, bA);
    if (nt + 8 < W) {
      const unsigned short* p = Bbase + ((size_t)((nt + 8) * 16) << 7);
#pragma unroll
      for (int sf = 0; sf < 4; ++sf) bA[sf] = load_frag(p + sf * 32);
    }
    if (ntB < W) compute_tile(ntB, bB);
  }
  __syncthreads();

  if (tid < 32) {
    const int i2 = tid >> 4, c = tid & 15;
    const float* wp = wmax + i2 * (16 * W) + c * W;
    float ssum = 0.f;
    for (int w = 0; w < W; ++w) ssum += wp[w];
    const int cc = cg0 + c;
    pooled[((i0 + i2) << 7) + cc] = ssum / (float)cap_l[cc];
  }
}

// 1024 blocks, one part-slice each (parallel layout; serializing measured
// ~2x slower in R3). LDS = 6.4 KB only; occupancy VGPR-bound (~2 blocks/CU).
__global__ __launch_bounds__(256, 2) void t2i_both(
    const unsigned short* __restrict__ imb, const unsigned short* __restrict__ sb,
    const unsigned short* __restrict__ pb,  const unsigned short* __restrict__ cb,
    const int* __restrict__ im_l, const int* __restrict__ s_l,
    const int* __restrict__ pred_l, const int* __restrict__ crl,
    float* __restrict__ p1, float* __restrict__ p2)
{
  __shared__ float wmax[2 * 16 * 50];
  if (blockIdx.x < 512)
    t2i_reg<3, 50>(imb, sb, im_l, s_l, p1, (int)blockIdx.x, wmax);
  else
    t2i_reg<2, 30>(pb, cb, pred_l, crl, p2, (int)blockIdx.x - 512, wmax);
}

// ---------------------------------------------------------------------------
// Hinge loss, simplified form validated in R1-R7:
//   max_j relu(M + S[i][j] - diag[i]) over the diag-zeroed matrix
//     == relu(M + offdiag_max_j(S[i][j]) - diag[i])
// One 256-thread block; kernel boundary provides p1/p2 coherence.
// ---------------------------------------------------------------------------
__global__ __launch_bounds__(256) void loss_kernel(
    const float* __restrict__ p1, const float* __restrict__ p2,
    float* __restrict__ out)
{
  __shared__ float cmax[2][128];
  __shared__ float rmax[2][128];
  __shared__ float wsum[2];
  const int tid = threadIdx.x;
  const int h = tid >> 7, j = tid & 127;

  {  // column off-diagonal max (coalesced: lanes sweep j for fixed row)
    float cm = -3.0e38f;
    for (int rr = 0; rr < 64; ++rr) {
      const int row = h * 64 + rr;
      const float v = p1[row * 128 + j] + p2[row * 128 + j];
      cm = (row == j) ? cm : fmaxf(cm, v);
    }
    cmax[h][j] = cm;
  }
  {  // row off-diagonal max (thread (h, i=j) scans its 64-col half of row i)
    float rm = -3.0e38f;
    for (int k = 0; k < 64; ++k) {
      const int c = h * 64 + k;
      const float v = p1[j * 128 + c] + p2[j * 128 + c];
      rm = (c == j) ? rm : fmaxf(rm, v);
    }
    rmax[h][j] = rm;
  }
  __syncthreads();

  float v = 0.f;
  if (tid < 128) {
    const float d  = p1[tid * 129] + p2[tid * 129];
    const float rm = fmaxf(rmax[0][tid], rmax[1][tid]);
    const float cm = fmaxf(cmax[0][tid], cmax[1][tid]);
    v = fmaxf(0.2f + rm - d, 0.f) + fmaxf(0.2f + cm - d, 0.f);
  }
#pragma unroll
  for (int o = 32; o; o >>= 1) v += __shfl_xor(v, o);
  if (tid == 0)  wsum[0] = v;
  if (tid == 64) wsum[1] = v;
  __syncthreads();
  if (tid == 0) out[0] = wsum[0] + wsum[1];
}

// ---------------------------------------------------------------------------
extern "C" void kernel_launch(void* const* d_in, const int* in_sizes, int n_in,
                              void* d_out, int out_size, void* d_ws, size_t ws_size,
                              hipStream_t stream)
{
  const float* im     = (const float*)d_in[0];
  const int*   im_l   = (const int*)  d_in[1];
  const float* s      = (const float*)d_in[2];
  const int*   s_l    = (const int*)  d_in[3];
  const float* pred   = (const float*)d_in[4];
  const int*   pred_l = (const int*)  d_in[5];
  // d_in[6], d_in[7] unused by the reference.
  const float* crp    = (const float*)d_in[8];
  const int*   crl    = (const int*)  d_in[9];

  char* ws = (char*)d_ws;
  const size_t off_imb = 0;
  const size_t off_sb  = off_imb + (size_t)128 * 48 * 128 * 2;
  const size_t off_pb  = off_sb  + (size_t)128 * 50 * 128 * 2;
  const size_t off_cb  = off_pb  + (size_t)128 * 32 * 128 * 2;
  const size_t off_p1  = off_cb  + (size_t)128 * 30 * 128 * 2;
  const size_t off_p2  = off_p1  + (size_t)128 * 128 * 4;

  unsigned short* imb = (unsigned short*)(ws + off_imb);
  unsigned short* sb  = (unsigned short*)(ws + off_sb);
  unsigned short* pb  = (unsigned short*)(ws + off_pb);
  unsigned short* cb  = (unsigned short*)(ws + off_cb);
  float* p1 = (float*)(ws + off_p1);
  float* p2 = (float*)(ws + off_p2);

  hipLaunchKernelGGL(convert_all, dim3(2560), dim3(256), 0, stream,
                     im, s, pred, crp, imb, sb, pb, cb);
  hipLaunchKernelGGL(t2i_both, dim3(1024), dim3(256), 0, stream,
                     imb, sb, pb, cb, im_l, s_l, pred_l, crl, p1, p2);
  hipLaunchKernelGGL(loss_kernel, dim3(1), dim3(256), 0, stream,
                     p1, p2, (float*)d_out);
}

// Round 9
// 120.286 us; speedup vs baseline: 1.2937x; 1.2161x over previous
//
#include <hip/hip_runtime.h>

typedef __bf16 bf16x8 __attribute__((ext_vector_type(8)));
typedef float f32x4 __attribute__((ext_vector_type(4)));
typedef unsigned int u32x4 __attribute__((ext_vector_type(4)));

__device__ __forceinline__ unsigned short f2bf(float f) {
  unsigned int u = __float_as_uint(f);
  u += 0x7FFFu + ((u >> 16) & 1u);   // round-to-nearest-even
  return (unsigned short)(u >> 16);
}

__device__ __forceinline__ bf16x8 load_frag(const unsigned short* p) {
  u32x4 v = *(const u32x4*)p;
  return __builtin_bit_cast(bf16x8, v);
}

// ---------------------------------------------------------------------------
// Convert all four used fp32 tensors to bf16 (object dims zero-padded to a
// multiple of 16 for MFMA M-tiling). Verified in R1.
// ---------------------------------------------------------------------------
__global__ __launch_bounds__(256) void convert_all(
    const float* __restrict__ im, const float* __restrict__ s,
    const float* __restrict__ pred, const float* __restrict__ crp,
    unsigned short* __restrict__ imb, unsigned short* __restrict__ sb,
    unsigned short* __restrict__ pb, unsigned short* __restrict__ cb)
{
  int b = blockIdx.x;
  const float* src; unsigned short* dst; int O, OP, base;
  if (b < 768)       { src = im;   dst = imb; O = 36; OP = 48; base = 0; }
  else if (b < 1568) { src = s;    dst = sb;  O = 50; OP = 50; base = 768; }
  else if (b < 2080) { src = pred; dst = pb;  O = 25; OP = 32; base = 1568; }
  else               { src = crp;  dst = cb;  O = 30; OP = 30; base = 2080; }
  int tid = (b - base) * 256 + (int)threadIdx.x;          // one thread = 4 floats
  int total = 128 * OP * 32;
  if (tid >= total) return;
  int d4 = tid & 31;
  int o  = (tid >> 5) % OP;
  int bb = tid / (OP * 32);
  unsigned short r0 = 0, r1 = 0, r2 = 0, r3 = 0;
  if (o < O) {
    const float4 v = *(const float4*)(src + ((bb * O + o) << 7) + (d4 << 2));
    r0 = f2bf(v.x); r1 = f2bf(v.y); r2 = f2bf(v.z); r3 = f2bf(v.w);
  }
  ushort4 outv; outv.x = r0; outv.y = r1; outv.z = r2; outv.w = r3;
  *(ushort4*)(dst + (size_t)tid * 4) = outv;
}

// ---------------------------------------------------------------------------
// t2i pooled score, TWO images per block vs one 16-caption group (halves B
// L2 traffic vs R1). Same verified D mapping: col=lane&15 (B-row), row=
// (lane>>4)*4+reg (object).
// ---------------------------------------------------------------------------
template<int MT, int W>
__device__ __forceinline__ void t2i_im2(
    const unsigned short* __restrict__ A,    // [128, MT*16, 128] bf16
    const unsigned short* __restrict__ Bw,   // [128, W, 128] bf16
    const int* __restrict__ obj_l, const int* __restrict__ cap_l,
    float* __restrict__ pooled,              // [128,128] fp32
    int vb, float* wmax)                     // wmax LDS >= 2*16*W
{
  const int ig  = vb >> 3;             // 0..63 -> images 2*ig, 2*ig+1
  const int i0  = ig * 2;
  const int cg0 = (vb & 7) * 16;
  const int tid = threadIdx.x;
  const int wv = tid >> 6, lane = tid & 63;
  const int quad = lane >> 4, n16 = lane & 15;
  const int ol0 = obj_l[i0], ol1 = obj_l[i0 + 1];

  bf16x8 af[2][MT][4];
#pragma unroll
  for (int im = 0; im < 2; ++im) {
    const unsigned short* Ab =
        A + (((size_t)(i0 + im) * (MT * 16) + n16) << 7) + quad * 8;
#pragma unroll
    for (int t = 0; t < MT; ++t)
#pragma unroll
      for (int s = 0; s < 4; ++s)
        af[im][t][s] = load_frag(Ab + ((t * 16) << 7) + s * 32);
  }

  const unsigned short* Bbase = Bw + (((size_t)cg0 * W + n16) << 7) + quad * 8;

  for (int nt = wv; nt < W; nt += 4) {     // NT = 16*W/16 = W tiles, exact
    const unsigned short* bp = Bbase + ((nt * 16) << 7);
    bf16x8 bfrag[4];
#pragma unroll
    for (int s = 0; s < 4; ++s) bfrag[s] = load_frag(bp + s * 32);

    f32x4 acc[2][MT];
#pragma unroll
    for (int im = 0; im < 2; ++im)
#pragma unroll
      for (int t = 0; t < MT; ++t) { f32x4 z = {0.f,0.f,0.f,0.f}; acc[im][t] = z; }
#pragma unroll
    for (int s = 0; s < 4; ++s)
#pragma unroll
      for (int im = 0; im < 2; ++im)
#pragma unroll
        for (int t = 0; t < MT; ++t)
          acc[im][t] = __builtin_amdgcn_mfma_f32_16x16x32_bf16(
              af[im][t][s], bfrag[s], acc[im][t], 0, 0, 0);

#pragma unroll
    for (int im = 0; im < 2; ++im) {
      const int ol = im ? ol1 : ol0;
      float m = -3.0e38f;
#pragma unroll
      for (int t = 0; t < MT; ++t)
#pragma unroll
        for (int r = 0; r < 4; ++r) {
          int o = t * 16 + quad * 4 + r;
          if (o < ol) m = fmaxf(m, acc[im][t][r]);
        }
      m = fmaxf(m, __shfl_xor(m, 16));
      m = fmaxf(m, __shfl_xor(m, 32));
      if (quad == 0) wmax[im * (16 * W) + nt * 16 + n16] = m;
    }
  }
  __syncthreads();

  if (tid < 32) {
    const int im = tid >> 4, c = tid & 15;
    const float* wp = wmax + im * (16 * W) + c * W;
    float ssum = 0.f;
    for (int w = 0; w < W; ++w) ssum += wp[w];
    const int cc = cg0 + c;
    pooled[((i0 + im) << 7) + cc] = ssum / (float)cap_l[cc];
  }
}

__global__ __launch_bounds__(256) void t2i_both(
    const unsigned short* __restrict__ imb, const unsigned short* __restrict__ sb,
    const unsigned short* __restrict__ pb,  const unsigned short* __restrict__ cb,
    const int* __restrict__ im_l, const int* __restrict__ s_l,
    const int* __restrict__ pred_l, const int* __restrict__ crl,
    float* __restrict__ p1, float* __restrict__ p2)
{
  __shared__ float wmax[2 * 16 * 50];
  if (blockIdx.x < 512) t2i_im2<3, 50>(imb, sb, im_l, s_l, p1, blockIdx.x, wmax);
  else                  t2i_im2<2, 30>(pb, cb, pred_l, crl, p2, blockIdx.x - 512, wmax);
}

// ---------------------------------------------------------------------------
// Hinge loss, one block of 1024 threads, fully coalesced: thread (sub,j)
// scans 16 rows (j contiguous), computing row-hinge (diag[row]) and
// col-hinge (diag[j]) from the same load. Row max: wave shfl + LDS
// atomicMax on float bits (valid: hinges >= 0). Col max: register + LDS tree.
// ---------------------------------------------------------------------------
__global__ __launch_bounds__(1024) void loss_kernel(
    const float* __restrict__ p1, const float* __restrict__ p2,
    float* __restrict__ out)
{
  __shared__ float diag[128];
  __shared__ int   rowmaxi[128];
  __shared__ float colmax[8][128];
  __shared__ float wred[16];
  const int tid = threadIdx.x;
  const int sub = tid >> 7, j = tid & 127;
  if (sub == 0) {
    diag[j] = p1[j * 129] + p2[j * 129];
    rowmaxi[j] = 0;                         // float bits of 0.0f
  }
  __syncthreads();

  float colp = 0.f;
#pragma unroll
  for (int rr = 0; rr < 16; ++rr) {
    const int row = sub * 16 + rr;
    const float sc = p1[row * 128 + j] + p2[row * 128 + j];
    const float dr = diag[row];
    float rh = (j == row) ? 0.f : fmaxf(0.2f + sc - dr, 0.f);
    const float ch = (j == row) ? 0.f : fmaxf(0.2f + sc - diag[j], 0.f);
    colp = fmaxf(colp, ch);
#pragma unroll
    for (int o = 32; o; o >>= 1) rh = fmaxf(rh, __shfl_xor(rh, o));
    if ((tid & 63) == 0) atomicMax(&rowmaxi[row], __float_as_int(rh));
  }
  colmax[sub][j] = colp;
  __syncthreads();
  if (sub < 4) colmax[sub][j] = fmaxf(colmax[sub][j], colmax[sub + 4][j]);
  __syncthreads();
  if (sub < 2) colmax[sub][j] = fmaxf(colmax[sub][j], colmax[sub + 2][j]);
  __syncthreads();
  if (sub < 1) colmax[0][j] = fmaxf(colmax[0][j], colmax[1][j]);
  __syncthreads();

  float v = 0.f;
  if (tid < 128)      v = __int_as_float(rowmaxi[tid]);
  else if (tid < 256) v = colmax[0][tid - 128];
#pragma unroll
  for (int o = 32; o; o >>= 1) v += __shfl_xor(v, o);
  if ((tid & 63) == 0) wred[tid >> 6] = v;
  __syncthreads();
  if (tid == 0) {
    float sfin = 0.f;
    for (int k = 0; k < 16; ++k) sfin += wred[k];
    out[0] = sfin;
  }
}

// ---------------------------------------------------------------------------
extern "C" void kernel_launch(void* const* d_in, const int* in_sizes, int n_in,
                              void* d_out, int out_size, void* d_ws, size_t ws_size,
                              hipStream_t stream)
{
  const float* im     = (const float*)d_in[0];
  const int*   im_l   = (const int*)  d_in[1];
  const float* s      = (const float*)d_in[2];
  const int*   s_l    = (const int*)  d_in[3];
  const float* pred   = (const float*)d_in[4];
  const int*   pred_l = (const int*)  d_in[5];
  // d_in[6], d_in[7] unused by the reference.
  const float* crp    = (const float*)d_in[8];
  const int*   crl    = (const int*)  d_in[9];

  char* ws = (char*)d_ws;
  const size_t off_imb = 0;
  const size_t off_sb  = off_imb + (size_t)128 * 48 * 128 * 2;
  const size_t off_pb  = off_sb  + (size_t)128 * 50 * 128 * 2;
  const size_t off_cb  = off_pb  + (size_t)128 * 32 * 128 * 2;
  const size_t off_p1  = off_cb  + (size_t)128 * 30 * 128 * 2;
  const size_t off_p2  = off_p1  + (size_t)128 * 128 * 4;

  unsigned short* imb = (unsigned short*)(ws + off_imb);
  unsigned short* sb  = (unsigned short*)(ws + off_sb);
  unsigned short* pb  = (unsigned short*)(ws + off_pb);
  unsigned short* cb  = (unsigned short*)(ws + off_cb);
  float* p1 = (float*)(ws + off_p1);
  float* p2 = (float*)(ws + off_p2);

  hipLaunchKernelGGL(convert_all, dim3(2560), dim3(256), 0, stream,
                     im, s, pred, crp, imb, sb, pb, cb);
  hipLaunchKernelGGL(t2i_both, dim3(1024), dim3(256), 0, stream,
                     imb, sb, pb, cb, im_l, s_l, pred_l, crl, p1, p2);
  hipLaunchKernelGGL(loss_kernel, dim3(1), dim3(1024), 0, stream,
                     p1, p2, (float*)d_out);
}